// Round 3
// baseline (186.281 us; speedup 1.0000x reference)
//
#include <hip/hip_runtime.h>

// Problem shapes (fixed by reference setup_inputs)
#define B_DIM 1024
#define C_DIM 128
#define K_DIM 1024
#define E_DIM 4
// cw_embed = B * C * E floats, then one_hot = B * C * K floats
#define EMBED_ELEMS (B_DIM * C_DIM * E_DIM)

// One wave handles 8 b-rows for a fixed c. 4 waves/block -> 32 b per block.
// Grid = C * (B/32) = 128 * 32 = 4096 blocks.
__global__ __launch_bounds__(256) void vqvae_kernel(
    const float* __restrict__ cw_q,      // (B, C*E) f32
    const float* __restrict__ codebook,  // (C, K, E) f32
    float* __restrict__ out)             // [embed | one_hot] f32
{
    const int lane = threadIdx.x & 63;
    const int wave = threadIdx.x >> 6;
    const int bid  = blockIdx.x;
    const int c      = bid >> 5;       // 32 blocks per c
    const int btile  = bid & 31;
    const int b_base = btile * 32 + wave * 8;

    const float4* cb4 = (const float4*)codebook + (size_t)c * K_DIM; // K float4 entries
    const float4* x4  = (const float4*)cw_q;                         // (B, C) float4
    float4* emb4 = (float4*)out;                                     // (B, C) float4
    float*  oh   = out + EMBED_ELEMS;

    // Register-cache this c's codebook: lane owns k = j*64 + lane, j=0..15.
    float4 cb[16];
#pragma unroll
    for (int j = 0; j < 16; ++j) {
        cb[j] = cb4[j * 64 + lane];
    }

    for (int i = 0; i < 8; ++i) {
        const int b = b_base + i;
        const float4 x = x4[(size_t)b * C_DIM + c];
        const double xx = (double)x.x, xy = (double)x.y,
                     xz = (double)x.z, xw = (double)x.w;

        // True (f64 direct) squared distance -> matches the referee's argmin.
        double best = 1.0e300;
        int    bi   = 0x7fffffff;
#pragma unroll
        for (int j = 0; j < 16; ++j) {
            const double dx = xx - (double)cb[j].x;
            const double dy = xy - (double)cb[j].y;
            const double dz = xz - (double)cb[j].z;
            const double dw = xw - (double)cb[j].w;
            const double d  = dx * dx + dy * dy + dz * dz + dw * dw;
            const int    k  = j * 64 + lane;
            if (d < best) { best = d; bi = k; }   // strict <: lowest k wins ties
        }

        // Wave-wide argmin with lowest-index tie-break (lexicographic (d, k) min).
#pragma unroll
        for (int off = 32; off >= 1; off >>= 1) {
            const double od = __shfl_xor(best, off);
            const int    oi = __shfl_xor(bi,   off);
            if (od < best || (od == best && oi < bi)) { best = od; bi = oi; }
        }
        // All lanes now agree on bi.

        // One-hot row: (b*C + c) * K floats, written as 4 float4 per lane.
        float4* row4 = (float4*)(oh + (size_t)(b * C_DIM + c) * K_DIM);
#pragma unroll
        for (int it = 0; it < 4; ++it) {
            const int f  = it * 64 + lane;
            const int k0 = f * 4;
            float4 v;
            v.x = (k0 + 0 == bi) ? 1.0f : 0.0f;
            v.y = (k0 + 1 == bi) ? 1.0f : 0.0f;
            v.z = (k0 + 2 == bi) ? 1.0f : 0.0f;
            v.w = (k0 + 3 == bi) ? 1.0f : 0.0f;
            row4[f] = v;
        }

        // cw_embed: single L2-hit gather (avoids runtime-indexed register array).
        if (lane == 0) {
            emb4[(size_t)b * C_DIM + c] = cb4[bi];
        }
    }
}

extern "C" void kernel_launch(void* const* d_in, const int* in_sizes, int n_in,
                              void* d_out, int out_size, void* d_ws, size_t ws_size,
                              hipStream_t stream) {
    const float* cw_q     = (const float*)d_in[0];
    const float* codebook = (const float*)d_in[1];
    float* out = (float*)d_out;

    const int blocks = C_DIM * (B_DIM / 32);  // 4096
    vqvae_kernel<<<blocks, 256, 0, stream>>>(cw_q, codebook, out);
}